// Round 8
// baseline (72.937 us; speedup 1.0000x reference)
//
#include <hip/hip_runtime.h>
#include <math.h>

// VanillaSFNN: B=1024, T=1024, H=256, IN=2, OUT=2, DECAY=0.8
// Round 8: speculative dual-path LIF step (compare off the critical path).
// u = pre-reset potential. Per step, compute BOTH continuations
//   fa = alpha*u + beta*cur   (no spike)   [= reference when sp=0]
//   fb = alpha*(u-1) + beta*cur (spike)    [u-1 rounds exactly like ref v-sp]
// while cmp(u>=1) resolves in parallel; cndmask picks. Serial path/step:
// mul->add->cnd (~24cy) vs R7's mul->add->cmp->mask->cnd->add (~40cy).
// Everything else = R7: block=128 (2 waves/SIMD), plain 8KB LDS x, op_sel
// broadcast, 4-entry ring prefetch. Bit-exact vs numpy reference.

constexpr int T_STEPS = 1024;
constexpr int HIDDEN  = 256;
constexpr int BLK     = 128;
constexpr int NENT    = T_STEPS / 2;   // 512 entries, 2 steps each

typedef float f32x2 __attribute__((ext_vector_type(2)));
typedef float f32x4 __attribute__((ext_vector_type(4)));

static __device__ __forceinline__ f32x2 pk_mul(f32x2 a, f32x2 b) {
    f32x2 d; asm("v_pk_mul_f32 %0, %1, %2" : "=v"(d) : "v"(a), "v"(b)); return d;
}
static __device__ __forceinline__ f32x2 pk_add(f32x2 a, f32x2 b) {
    f32x2 d; asm("v_pk_add_f32 %0, %1, %2" : "=v"(d) : "v"(a), "v"(b)); return d;
}
static __device__ __forceinline__ f32x2 pk_fma(f32x2 a, f32x2 b, f32x2 c) {
    f32x2 d; asm("v_pk_fma_f32 %0, %1, %2, %3" : "=v"(d) : "v"(a), "v"(b), "v"(c)); return d;
}
// lo = x.lo*w.lo, hi = x.lo*w.hi  (broadcast word0 of x)
static __device__ __forceinline__ f32x2 pk_mul_bc0(f32x2 x, f32x2 w) {
    f32x2 d; asm("v_pk_mul_f32 %0, %1, %2 op_sel:[0,0] op_sel_hi:[0,1]"
                 : "=v"(d) : "v"(x), "v"(w)); return d;
}
// lo = x.hi*w.lo, hi = x.hi*w.hi  (broadcast word1 of x)
static __device__ __forceinline__ f32x2 pk_mul_bc1(f32x2 x, f32x2 w) {
    f32x2 d; asm("v_pk_mul_f32 %0, %1, %2 op_sel:[1,0] op_sel_hi:[1,1]"
                 : "=v"(d) : "v"(x), "v"(w)); return d;
}

__global__ __launch_bounds__(BLK) void sfnn_spec_kernel(
    const float* __restrict__ x_seq,   // [B, T, 2]
    const float* __restrict__ W_in,    // [H, 2]
    const float* __restrict__ b_in,    // [H]
    const float* __restrict__ W_out,   // [2, H]
    const float* __restrict__ b_out,   // [2]
    const float* __restrict__ tau_m,   // [H]
    float* __restrict__ out)           // [B, 2]
{
    __shared__ f32x4 xs[NENT];         // 8 KB: plain x[b]
    __shared__ float red[4];           // cross-wave epilogue partials

    const int b   = blockIdx.x;
    const int tid = threadIdx.x;
    const int h0  = tid;
    const int h1  = tid + BLK;

    // --- stage x[b] into LDS (coalesced 16B, conflict-free) ---
    const f32x4* __restrict__ xg =
        reinterpret_cast<const f32x4*>(x_seq) + (size_t)b * NENT;
    #pragma unroll
    for (int k = 0; k < NENT / BLK; ++k)
        xs[tid + k * BLK] = xg[tid + k * BLK];

    // --- per-lane packed constants ---
    f32x2 w0p, w1p, bip, alp, bep, c08, cm1;
    w0p.x = W_in[2 * h0];     w0p.y = W_in[2 * h1];
    w1p.x = W_in[2 * h0 + 1]; w1p.y = W_in[2 * h1 + 1];
    bip.x = b_in[h0];         bip.y = b_in[h1];
    alp.x = 1.0f / (1.0f + expf(-tau_m[h0]));
    alp.y = 1.0f / (1.0f + expf(-tau_m[h1]));
    bep.x = 1.0f - alp.x;     bep.y = 1.0f - alp.y;
    c08.x = 0.8f;             c08.y = 0.8f;
    cm1.x = -1.0f;            cm1.y = -1.0f;

    __syncthreads();

    f32x2 u  = {0.0f, 0.0f};   // pre-reset potential (u_{-1} = 0, no spike)
    f32x2 Sn = {0.0f, 0.0f};   // negated decayed spike sum (lags one step)

    // speculative step: consumes bc = beta*cur for step t, applies spike of
    // step t-1 to Sn, produces u_t. cmp(u>=1) resolves parallel to fa/fb.
    #define SPEC_STEP(BC)                                                     \
        {                                                                     \
            const bool mx = (u.x >= 1.0f);                                    \
            const bool my = (u.y >= 1.0f);                                    \
            f32x2 um1 = pk_add(u, cm1);                                       \
            f32x2 fa  = pk_add(pk_mul(u,   alp), (BC));                       \
            f32x2 fb  = pk_add(pk_mul(um1, alp), (BC));                       \
            f32x2 spn;                                                        \
            spn.x = mx ? -1.0f : 0.0f;                                        \
            spn.y = my ? -1.0f : 0.0f;                                        \
            u.x = mx ? fb.x : fa.x;                                           \
            u.y = my ? fb.y : fa.y;                                           \
            Sn = pk_fma(c08, Sn, spn);                                        \
        }

    // per ring entry (2 steps): hoist cur/bc for both steps, then 2 specs
    #define LIF2(Q)                                                           \
        {                                                                     \
            f32x2 xlo = __builtin_shufflevector((Q), (Q), 0, 1);              \
            f32x2 xhi = __builtin_shufflevector((Q), (Q), 2, 3);              \
            f32x2 cur0 = pk_add(pk_add(pk_mul_bc0(xlo, w0p),                  \
                                       pk_mul_bc1(xlo, w1p)), bip);           \
            f32x2 cur1 = pk_add(pk_add(pk_mul_bc0(xhi, w0p),                  \
                                       pk_mul_bc1(xhi, w1p)), bip);           \
            f32x2 bc0 = pk_mul(bep, cur0);                                    \
            f32x2 bc1 = pk_mul(bep, cur1);                                    \
            SPEC_STEP(bc0)                                                    \
            SPEC_STEP(bc1)                                                    \
        }

    // --- main loop: 4-entry register ring (prefetch distance 4 = 8 steps) ---
    f32x4 q0 = xs[0];
    f32x4 q1 = xs[1];
    f32x4 q2 = xs[2];
    f32x4 q3 = xs[3];
    for (int i = 0; i < NENT - 4; i += 4) {
        LIF2(q0) q0 = xs[i + 4];
        LIF2(q1) q1 = xs[i + 5];
        LIF2(q2) q2 = xs[i + 6];
        LIF2(q3) q3 = xs[i + 7];
    }
    LIF2(q0) LIF2(q1) LIF2(q2) LIF2(q3)
    #undef LIF2
    #undef SPEC_STEP

    // --- trailing spike of step T-1 ---
    {
        f32x2 spn;
        spn.x = (u.x >= 1.0f) ? -1.0f : 0.0f;
        spn.y = (u.y >= 1.0f) ? -1.0f : 0.0f;
        Sn = pk_fma(c08, Sn, spn);
    }

    // --- epilogue: project -Sn onto W_out, wave shuffle-reduce, combine ---
    const float Sx = -Sn.x, Sy = -Sn.y;
    float r0 = fmaf(Sy, W_out[h1],          Sx * W_out[h0]);
    float r1 = fmaf(Sy, W_out[HIDDEN + h1], Sx * W_out[HIDDEN + h0]);
    #pragma unroll
    for (int off = 32; off > 0; off >>= 1) {
        r0 += __shfl_xor(r0, off, 64);
        r1 += __shfl_xor(r1, off, 64);
    }
    const int wave = tid >> 6;
    if ((tid & 63) == 0) {
        red[2 * wave]     = r0;
        red[2 * wave + 1] = r1;
    }
    __syncthreads();
    if (tid == 0) {
        const float geo = 5.0f;   // sum_{k=0}^{1023} 0.8^k rounds to 5.0f
        out[2 * b]     = (red[0] + red[2]) + b_out[0] * geo;
        out[2 * b + 1] = (red[1] + red[3]) + b_out[1] * geo;
    }
}

extern "C" void kernel_launch(void* const* d_in, const int* in_sizes, int n_in,
                              void* d_out, int out_size, void* d_ws, size_t ws_size,
                              hipStream_t stream) {
    const float* x_seq = (const float*)d_in[0];
    const float* W_in  = (const float*)d_in[1];
    const float* b_in  = (const float*)d_in[2];
    const float* W_out = (const float*)d_in[3];
    const float* b_out = (const float*)d_in[4];
    const float* tau_m = (const float*)d_in[5];
    float* out = (float*)d_out;

    sfnn_spec_kernel<<<dim3(1024), dim3(BLK), 0, stream>>>(
        x_seq, W_in, b_in, W_out, b_out, tau_m, out);
}

// Round 9
// 59.412 us; speedup vs baseline: 1.2277x; 1.2277x over previous
//
#include <hip/hip_runtime.h>
#include <math.h>

// VanillaSFNN: B=1024, T=1024, H=256, IN=2, OUT=2, DECAY=0.8
// Round 9 = R7 (best, 62.4us) with ONE change: spike select computed as
//   spn = fmed3(-floor(v), -1, 0)   in {-1, 0}
// instead of v_cmp + v_cndmask. Pure VALU dataflow — no vcc write->read
// round-trip, .x/.y resolve in parallel. Bit-exact: floor(v) is an exact
// integer; med3 selects exactly -1 or 0; v + (-1) == v - spike.
// Structure: block=128, grid=1024 (2 waves/SIMD), plain 8KB LDS x with
// op_sel broadcast, 4-entry register ring (prefetch distance 4 = 8 steps).

constexpr int T_STEPS = 1024;
constexpr int HIDDEN  = 256;
constexpr int BLK     = 128;
constexpr int NENT    = T_STEPS / 2;   // 512 entries, 2 steps each

typedef float f32x2 __attribute__((ext_vector_type(2)));
typedef float f32x4 __attribute__((ext_vector_type(4)));

static __device__ __forceinline__ f32x2 pk_mul(f32x2 a, f32x2 b) {
    f32x2 d; asm("v_pk_mul_f32 %0, %1, %2" : "=v"(d) : "v"(a), "v"(b)); return d;
}
static __device__ __forceinline__ f32x2 pk_add(f32x2 a, f32x2 b) {
    f32x2 d; asm("v_pk_add_f32 %0, %1, %2" : "=v"(d) : "v"(a), "v"(b)); return d;
}
static __device__ __forceinline__ f32x2 pk_fma(f32x2 a, f32x2 b, f32x2 c) {
    f32x2 d; asm("v_pk_fma_f32 %0, %1, %2, %3" : "=v"(d) : "v"(a), "v"(b), "v"(c)); return d;
}
// lo = x.lo*w.lo, hi = x.lo*w.hi  (broadcast word0 of x)
static __device__ __forceinline__ f32x2 pk_mul_bc0(f32x2 x, f32x2 w) {
    f32x2 d; asm("v_pk_mul_f32 %0, %1, %2 op_sel:[0,0] op_sel_hi:[0,1]"
                 : "=v"(d) : "v"(x), "v"(w)); return d;
}
// lo = x.hi*w.lo, hi = x.hi*w.hi  (broadcast word1 of x)
static __device__ __forceinline__ f32x2 pk_mul_bc1(f32x2 x, f32x2 w) {
    f32x2 d; asm("v_pk_mul_f32 %0, %1, %2 op_sel:[1,0] op_sel_hi:[1,1]"
                 : "=v"(d) : "v"(x), "v"(w)); return d;
}
// spn = med3(-floor(v), -1, 0)  in {-1,0};  -1 iff v >= 1
static __device__ __forceinline__ float spike_neg(float v) {
    return __builtin_amdgcn_fmed3f(-floorf(v), -1.0f, 0.0f);
}

__global__ __launch_bounds__(BLK) void sfnn_med3_kernel(
    const float* __restrict__ x_seq,   // [B, T, 2]
    const float* __restrict__ W_in,    // [H, 2]
    const float* __restrict__ b_in,    // [H]
    const float* __restrict__ W_out,   // [2, H]
    const float* __restrict__ b_out,   // [2]
    const float* __restrict__ tau_m,   // [H]
    float* __restrict__ out)           // [B, 2]
{
    __shared__ f32x4 xs[NENT];         // 8 KB: plain x[b]
    __shared__ float red[4];           // cross-wave epilogue partials

    const int b   = blockIdx.x;
    const int tid = threadIdx.x;
    const int h0  = tid;
    const int h1  = tid + BLK;

    // --- stage x[b] into LDS (coalesced 16B, conflict-free) ---
    const f32x4* __restrict__ xg =
        reinterpret_cast<const f32x4*>(x_seq) + (size_t)b * NENT;
    #pragma unroll
    for (int k = 0; k < NENT / BLK; ++k)
        xs[tid + k * BLK] = xg[tid + k * BLK];

    // --- per-lane packed constants ---
    f32x2 w0p, w1p, bip, alp, bep, c08;
    w0p.x = W_in[2 * h0];     w0p.y = W_in[2 * h1];
    w1p.x = W_in[2 * h0 + 1]; w1p.y = W_in[2 * h1 + 1];
    bip.x = b_in[h0];         bip.y = b_in[h1];
    alp.x = 1.0f / (1.0f + expf(-tau_m[h0]));
    alp.y = 1.0f / (1.0f + expf(-tau_m[h1]));
    bep.x = 1.0f - alp.x;     bep.y = 1.0f - alp.y;
    c08.x = 0.8f;             c08.y = 0.8f;

    __syncthreads();

    f32x2 v  = {0.0f, 0.0f};
    f32x2 Sn = {0.0f, 0.0f};           // negated decayed spike sum

    // one LIF step for both h-units; xp = {x0(t), x1(t)}
    #define LIF_STEP(XP)                                                      \
        {                                                                     \
            f32x2 cur = pk_add(pk_add(pk_mul_bc0((XP), w0p),                  \
                                      pk_mul_bc1((XP), w1p)), bip);           \
            v = pk_add(pk_mul(v, alp), pk_mul(bep, cur));                     \
            f32x2 spn;                                                        \
            spn.x = spike_neg(v.x);                                           \
            spn.y = spike_neg(v.y);                                           \
            v  = pk_add(v, spn);                                              \
            Sn = pk_fma(c08, Sn, spn);                                        \
        }
    #define LIF2(Q)                                                           \
        LIF_STEP(__builtin_shufflevector((Q), (Q), 0, 1))                     \
        LIF_STEP(__builtin_shufflevector((Q), (Q), 2, 3))

    // --- main loop: 4-entry register ring (prefetch distance 4 = 8 steps) ---
    f32x4 q0 = xs[0];
    f32x4 q1 = xs[1];
    f32x4 q2 = xs[2];
    f32x4 q3 = xs[3];
    for (int i = 0; i < NENT - 4; i += 4) {
        LIF2(q0) q0 = xs[i + 4];
        LIF2(q1) q1 = xs[i + 5];
        LIF2(q2) q2 = xs[i + 6];
        LIF2(q3) q3 = xs[i + 7];
    }
    LIF2(q0) LIF2(q1) LIF2(q2) LIF2(q3)
    #undef LIF2
    #undef LIF_STEP

    // --- epilogue: project -Sn onto W_out, wave shuffle-reduce, combine ---
    const float Sx = -Sn.x, Sy = -Sn.y;
    float r0 = fmaf(Sy, W_out[h1],          Sx * W_out[h0]);
    float r1 = fmaf(Sy, W_out[HIDDEN + h1], Sx * W_out[HIDDEN + h0]);
    #pragma unroll
    for (int off = 32; off > 0; off >>= 1) {
        r0 += __shfl_xor(r0, off, 64);
        r1 += __shfl_xor(r1, off, 64);
    }
    const int wave = tid >> 6;
    if ((tid & 63) == 0) {
        red[2 * wave]     = r0;
        red[2 * wave + 1] = r1;
    }
    __syncthreads();
    if (tid == 0) {
        const float geo = 5.0f;   // sum_{k=0}^{1023} 0.8^k rounds to 5.0f
        out[2 * b]     = (red[0] + red[2]) + b_out[0] * geo;
        out[2 * b + 1] = (red[1] + red[3]) + b_out[1] * geo;
    }
}

extern "C" void kernel_launch(void* const* d_in, const int* in_sizes, int n_in,
                              void* d_out, int out_size, void* d_ws, size_t ws_size,
                              hipStream_t stream) {
    const float* x_seq = (const float*)d_in[0];
    const float* W_in  = (const float*)d_in[1];
    const float* b_in  = (const float*)d_in[2];
    const float* W_out = (const float*)d_in[3];
    const float* b_out = (const float*)d_in[4];
    const float* tau_m = (const float*)d_in[5];
    float* out = (float*)d_out;

    sfnn_med3_kernel<<<dim3(1024), dim3(BLK), 0, stream>>>(
        x_seq, W_in, b_in, W_out, b_out, tau_m, out);
}

// Round 10
// 57.794 us; speedup vs baseline: 1.2620x; 1.0280x over previous
//
#include <hip/hip_runtime.h>
#include <math.h>

// VanillaSFNN: B=1024, T=1024, H=256, IN=2, OUT=2, DECAY=0.8
// Round 10 = R9 (59.4us) with the LDS path removed from the main loop:
// x[b] is WAVE-UNIFORM -> read it through the scalar pipe (s_load) into an
// SGPR ring, and feed v_pk_mul_f32 directly from the SGPR pair via op_sel
// broadcast ("s" constraint, 1 scalar source = legal). Removes staging,
// pre-loop barrier, all ds_reads; ring rotation becomes SALU (free issue).
// Waves decouple (no lockstep barrier) -> stalls decorrelate.
// Arithmetic identical to R9 (med3 spike, packed v/Sn) -> bit-exact.

constexpr int T_STEPS = 1024;
constexpr int HIDDEN  = 256;
constexpr int BLK     = 128;
constexpr int NENT    = T_STEPS / 2;   // 512 f32x4 entries, 2 steps each

typedef float f32x2 __attribute__((ext_vector_type(2)));
typedef float f32x4 __attribute__((ext_vector_type(4)));

static __device__ __forceinline__ f32x2 pk_mul(f32x2 a, f32x2 b) {
    f32x2 d; asm("v_pk_mul_f32 %0, %1, %2" : "=v"(d) : "v"(a), "v"(b)); return d;
}
static __device__ __forceinline__ f32x2 pk_add(f32x2 a, f32x2 b) {
    f32x2 d; asm("v_pk_add_f32 %0, %1, %2" : "=v"(d) : "v"(a), "v"(b)); return d;
}
static __device__ __forceinline__ f32x2 pk_fma(f32x2 a, f32x2 b, f32x2 c) {
    f32x2 d; asm("v_pk_fma_f32 %0, %1, %2, %3" : "=v"(d) : "v"(a), "v"(b), "v"(c)); return d;
}
// lo = x.lo*w.lo, hi = x.lo*w.hi  (x from SGPR pair, broadcast word0)
static __device__ __forceinline__ f32x2 pk_mul_bc0s(f32x2 x, f32x2 w) {
    f32x2 d; asm("v_pk_mul_f32 %0, %1, %2 op_sel:[0,0] op_sel_hi:[0,1]"
                 : "=v"(d) : "s"(x), "v"(w)); return d;
}
// lo = x.hi*w.lo, hi = x.hi*w.hi  (x from SGPR pair, broadcast word1)
static __device__ __forceinline__ f32x2 pk_mul_bc1s(f32x2 x, f32x2 w) {
    f32x2 d; asm("v_pk_mul_f32 %0, %1, %2 op_sel:[1,0] op_sel_hi:[1,1]"
                 : "=v"(d) : "s"(x), "v"(w)); return d;
}
// spn = med3(-floor(v), -1, 0) in {-1,0};  -1 iff v >= 1
static __device__ __forceinline__ float spike_neg(float v) {
    return __builtin_amdgcn_fmed3f(-floorf(v), -1.0f, 0.0f);
}

__global__ __launch_bounds__(BLK) void sfnn_smem_kernel(
    const float* __restrict__ x_seq,   // [B, T, 2]
    const float* __restrict__ W_in,    // [H, 2]
    const float* __restrict__ b_in,    // [H]
    const float* __restrict__ W_out,   // [2, H]
    const float* __restrict__ b_out,   // [2]
    const float* __restrict__ tau_m,   // [H]
    float* __restrict__ out)           // [B, 2]
{
    __shared__ float red[4];           // cross-wave epilogue partials only

    const int b   = blockIdx.x;
    const int tid = threadIdx.x;
    const int h0  = tid;
    const int h1  = tid + BLK;

    // wave-uniform base for x[b] -> compiler emits s_load for xg[i]
    const f32x4* __restrict__ xg =
        reinterpret_cast<const f32x4*>(x_seq) + (size_t)b * NENT;

    // --- per-lane packed constants ---
    f32x2 w0p, w1p, bip, alp, bep, c08;
    w0p.x = W_in[2 * h0];     w0p.y = W_in[2 * h1];
    w1p.x = W_in[2 * h0 + 1]; w1p.y = W_in[2 * h1 + 1];
    bip.x = b_in[h0];         bip.y = b_in[h1];
    alp.x = 1.0f / (1.0f + expf(-tau_m[h0]));
    alp.y = 1.0f / (1.0f + expf(-tau_m[h1]));
    bep.x = 1.0f - alp.x;     bep.y = 1.0f - alp.y;
    c08.x = 0.8f;             c08.y = 0.8f;

    f32x2 v  = {0.0f, 0.0f};
    f32x2 Sn = {0.0f, 0.0f};           // negated decayed spike sum

    // one LIF step for both h-units; XP = uniform {x0(t), x1(t)} in SGPRs
    #define LIF_STEP(XP)                                                      \
        {                                                                     \
            f32x2 cur = pk_add(pk_add(pk_mul_bc0s((XP), w0p),                 \
                                      pk_mul_bc1s((XP), w1p)), bip);          \
            v = pk_add(pk_mul(v, alp), pk_mul(bep, cur));                     \
            f32x2 spn;                                                        \
            spn.x = spike_neg(v.x);                                           \
            spn.y = spike_neg(v.y);                                           \
            v  = pk_add(v, spn);                                              \
            Sn = pk_fma(c08, Sn, spn);                                        \
        }
    #define LIF2(Q)                                                           \
        LIF_STEP(__builtin_shufflevector((Q), (Q), 0, 1))                     \
        LIF_STEP(__builtin_shufflevector((Q), (Q), 2, 3))

    // --- main loop: 4-entry SGPR ring (prefetch distance 4 = 8 steps) ---
    f32x4 q0 = xg[0];
    f32x4 q1 = xg[1];
    f32x4 q2 = xg[2];
    f32x4 q3 = xg[3];
    for (int i = 0; i < NENT - 4; i += 4) {
        LIF2(q0) q0 = xg[i + 4];
        LIF2(q1) q1 = xg[i + 5];
        LIF2(q2) q2 = xg[i + 6];
        LIF2(q3) q3 = xg[i + 7];
    }
    LIF2(q0) LIF2(q1) LIF2(q2) LIF2(q3)
    #undef LIF2
    #undef LIF_STEP

    // --- epilogue: project -Sn onto W_out, wave shuffle-reduce, combine ---
    const float Sx = -Sn.x, Sy = -Sn.y;
    float r0 = fmaf(Sy, W_out[h1],          Sx * W_out[h0]);
    float r1 = fmaf(Sy, W_out[HIDDEN + h1], Sx * W_out[HIDDEN + h0]);
    #pragma unroll
    for (int off = 32; off > 0; off >>= 1) {
        r0 += __shfl_xor(r0, off, 64);
        r1 += __shfl_xor(r1, off, 64);
    }
    const int wave = tid >> 6;
    if ((tid & 63) == 0) {
        red[2 * wave]     = r0;
        red[2 * wave + 1] = r1;
    }
    __syncthreads();
    if (tid == 0) {
        const float geo = 5.0f;   // sum_{k=0}^{1023} 0.8^k rounds to 5.0f
        out[2 * b]     = (red[0] + red[2]) + b_out[0] * geo;
        out[2 * b + 1] = (red[1] + red[3]) + b_out[1] * geo;
    }
}

extern "C" void kernel_launch(void* const* d_in, const int* in_sizes, int n_in,
                              void* d_out, int out_size, void* d_ws, size_t ws_size,
                              hipStream_t stream) {
    const float* x_seq = (const float*)d_in[0];
    const float* W_in  = (const float*)d_in[1];
    const float* b_in  = (const float*)d_in[2];
    const float* W_out = (const float*)d_in[3];
    const float* b_out = (const float*)d_in[4];
    const float* tau_m = (const float*)d_in[5];
    float* out = (float*)d_out;

    sfnn_smem_kernel<<<dim3(1024), dim3(BLK), 0, stream>>>(
        x_seq, W_in, b_in, W_out, b_out, tau_m, out);
}